// Round 1
// baseline (545.295 us; speedup 1.0000x reference)
//
#include <hip/hip_runtime.h>
#include <stdint.h>

// Transformer-XL relative attention scores, MI355X (gfx950).
// out[i,j,b,n] = AC + BD:
//   AC = (q+r_w_bias) . k           (per (b,n) head, contracted over d=64)
//   BD = rel_shift(B_ + D_):  j<=i  -> Bsum[i, 1023-(i-j)]
//                             j==i+1-> 0
//                             j>i+1 -> Bsum[i+1, j-i-2]
//   Bsum[i,jj] = q.r_emb[jj] + r_bias[jj]  computed as rw.r_emb + adj[jj,n],
//   adj[jj,n] = r_bias[jj,n] - r_w_bias[n].r_emb[jj,n]  (precomputed).
// fp32 accuracy via 3-term bf16 split MFMA (hi*hi + lo*hi + hi*lo).

typedef __bf16 v8bf __attribute__((ext_vector_type(8)));
typedef float f32x4 __attribute__((ext_vector_type(4)));

union U16x8 { uint4 q; unsigned short us[8]; v8bf v; };

__device__ __forceinline__ unsigned short bf_rne(float f) {
  unsigned int u = __float_as_uint(f);
  return (unsigned short)((u + 0x7fffu + ((u >> 16) & 1u)) >> 16);
}
__device__ __forceinline__ float bf2f(unsigned short h) {
  return __uint_as_float(((unsigned int)h) << 16);
}
__device__ __forceinline__ f32x4 mfma16(v8bf a, v8bf b, f32x4 c) {
  return __builtin_amdgcn_mfma_f32_16x16x32_bf16(a, b, c, 0, 0, 0);
}

template<int N> struct IC { static constexpr int value = N; };

// ---------------- prep: adj[n][jj] = r_bias[jj,n] - r_w_bias[n].r_emb[jj,n] ----
__global__ __launch_bounds__(256) void k_adj(
    const float* __restrict__ r_emb, const float* __restrict__ r_w_bias,
    const float* __restrict__ r_bias, float* __restrict__ adj) {
  int t = blockIdx.x * 256 + threadIdx.x;            // 16384 threads
  int n = t >> 10, jj = t & 1023;
  const float* re = r_emb + ((size_t)jj * 16 + n) * 64;
  const float* wb = r_w_bias + n * 64;
  float s = 0.f;
#pragma unroll
  for (int d = 0; d < 64; ++d) s += wb[d] * re[d];
  adj[n * 1024 + jj] = r_bias[jj * 16 + n] - s;
}

// ---------------- prep: pack K and R into bf16 hi/lo MFMA fragments -----------
// Block (tile, hl, kc) = 64 lanes x 8 bf16 = 1KB. lane l -> row=l&15,
// k = kc*32 + (l>>4)*8 + e. A and B use identical k packing (permutation-safe).
__global__ __launch_bounds__(256) void k_pack(
    const float* __restrict__ wk, const float* __restrict__ re,
    unsigned short* __restrict__ Kp, unsigned short* __restrict__ Rp) {
  __shared__ float ls[16][68];                       // +4 pad: kill 16-way read conflicts
  const int gid = blockIdx.x, t = threadIdx.x;
  const int rr = t >> 4, dq = t & 15;
  const float* src;
  unsigned short* dst;
  if (gid < 4096) {                                  // K tiles: c=gid>>6, jt=gid&63
    const int c = gid >> 6, jt = gid & 63, b = c >> 4, n = c & 15;
    src = wk + (size_t)(jt * 16 + rr) * 4096 + b * 1024 + n * 64;
    dst = Kp + (size_t)gid * 2048;
  } else {                                           // R tiles: n, T
    const int g = gid - 4096, n = g >> 6, T = g & 63;
    src = re + ((size_t)(T * 16 + rr) * 16 + n) * 64;
    dst = Rp + (size_t)g * 2048;
  }
  *(float4*)&ls[rr][dq * 4] = *(const float4*)(src + dq * 4);
  __syncthreads();
  const int hl = t >> 7, kc = (t >> 6) & 1, l = t & 63;
  const float* lp = &ls[l & 15][kc * 32 + (l >> 4) * 8];
  U16x8 o;
#pragma unroll
  for (int e = 0; e < 8; ++e) {
    float xe = lp[e];
    unsigned short hi = bf_rne(xe);
    o.us[e] = (hl == 0) ? hi : bf_rne(xe - bf2f(hi));
  }
  *(uint4*)(dst + (size_t)(hl * 2 + kc) * 512 + (size_t)l * 8) = o.q;
}

// ---------------- main fused kernel ------------------------------------------
// wg: i-block of 32 rows x c-group of 8 heads (1 head per wave), j-sweep 64x16.
// Bsum tiles scattered into 4-slot rotating LDS BD-window; epilogue writes
// c-contiguous 32B chunks (full HBM sectors).
__global__ __launch_bounds__(512, 2) void k_main(
    const float* __restrict__ q, const float* __restrict__ r_w_bias,
    const unsigned short* __restrict__ Kp_, const unsigned short* __restrict__ Rp_,
    const float* __restrict__ adj, float* __restrict__ out) {
  __shared__ float win[8][32][64];   // [c_local][row][colSlot]   64 KB
  __shared__ float outb[8][32][16];  // AC transpose staging      16 KB
  const int tid = threadIdx.x;
  const int w = tid >> 6, lane = tid & 63;
  const int lr = lane & 15, lh = lane >> 4;
  const int bid = blockIdx.x;
  const int cgrp = bid & 7, iblk = bid >> 3;         // cgrp=bid&7 -> XCD-local K/R
  const int i0 = iblk * 32, it0 = iblk * 2, c0 = cgrp * 8;
  const int c = c0 + w, n = c & 15, b = c >> 4;
  const uint4* Kp4 = (const uint4*)Kp_;
  const uint4* Rp4 = (const uint4*)Rp_;

  { // zero whole window (prologue needs halves 0..2 clean)
    float4 z = {0.f, 0.f, 0.f, 0.f};
    float4* wp = (float4*)(&win[0][0][0]);
#pragma unroll
    for (int kk = 0; kk < 8; ++kk) wp[tid + kk * 512] = z;
  }

  // ---- A fragments: rw = q + r_w_bias, rows i0+itl*16+lr, split hi/lo ----
  v8bf Ah[3][2], Al[3][2];
  {
    U16x8 z; z.q = uint4{0u, 0u, 0u, 0u};
#pragma unroll
    for (int itl = 0; itl < 3; ++itl)
#pragma unroll
      for (int kc = 0; kc < 2; ++kc) { Ah[itl][kc] = z.v; Al[itl][kc] = z.v; }
    float wbv[2][8];
#pragma unroll
    for (int kc = 0; kc < 2; ++kc) {
      float4 b0 = *(const float4*)(r_w_bias + n * 64 + kc * 32 + lh * 8);
      float4 b1 = *(const float4*)(r_w_bias + n * 64 + kc * 32 + lh * 8 + 4);
      wbv[kc][0] = b0.x; wbv[kc][1] = b0.y; wbv[kc][2] = b0.z; wbv[kc][3] = b0.w;
      wbv[kc][4] = b1.x; wbv[kc][5] = b1.y; wbv[kc][6] = b1.z; wbv[kc][7] = b1.w;
    }
#pragma unroll
    for (int itl = 0; itl < 3; ++itl) {
      if (it0 + itl <= 63) {
        const float* qp = q + (size_t)(i0 + itl * 16 + lr) * 4096 + b * 1024 + n * 64;
#pragma unroll
        for (int kc = 0; kc < 2; ++kc) {
          float4 xa = *(const float4*)(qp + kc * 32 + lh * 8);
          float4 xb = *(const float4*)(qp + kc * 32 + lh * 8 + 4);
          float x[8] = {xa.x, xa.y, xa.z, xa.w, xb.x, xb.y, xb.z, xb.w};
          U16x8 ph, pl;
#pragma unroll
          for (int e = 0; e < 8; ++e) {
            float xe = x[e] + wbv[kc][e];
            unsigned short hi = bf_rne(xe);
            ph.us[e] = hi;
            pl.us[e] = bf_rne(xe - bf2f(hi));
          }
          Ah[itl][kc] = ph.v; Al[itl][kc] = pl.v;
        }
      }
    }
  }

  // ---- B-operand registers: R 4-slot ring + K double buffer ----
  v8bf Rh[4][2], Rl[4][2], Kh[2][2], Kl[2][2];

  auto loadR = [&](auto SL, int T) {
    constexpr int S_ = decltype(SL)::value;
#pragma unroll
    for (int hl = 0; hl < 2; ++hl)
#pragma unroll
      for (int kc = 0; kc < 2; ++kc) {
        U16x8 u_;
        u_.q = Rp4[((size_t)(n * 64 + T) * 4 + hl * 2 + kc) * 64 + lane];
        if (hl == 0) Rh[S_][kc] = u_.v; else Rl[S_][kc] = u_.v;
      }
  };
  auto loadK = [&](auto BF, int jt) {
    constexpr int B_ = decltype(BF)::value;
#pragma unroll
    for (int hl = 0; hl < 2; ++hl)
#pragma unroll
      for (int kc = 0; kc < 2; ++kc) {
        U16x8 u_;
        u_.q = Kp4[((size_t)(c * 64 + jt) * 4 + hl * 2 + kc) * 64 + lane];
        if (hl == 0) Kh[B_][kc] = u_.v; else Kl[B_][kc] = u_.v;
      }
  };

  // step body. U == s&3 (U=3 for the s=-1 prologue). PRO: only band1 (u>=1023)
  // elements are scattered (the "m=63" boundary tiles feeding step 0).
  auto body = [&](auto UC, auto PC, int s) {
    constexpr int U = decltype(UC)::value;
    constexpr bool PRO = (decltype(PC)::value != 0);
    if (PRO) loadK(IC<(U + 1) & 1>{}, 0);
    else if (s < 63) loadK(IC<(U + 1) & 1>{}, s + 1);     // K prefetch
    loadR(IC<(U + 1) & 3>{}, (s + 1 - it0) & 63);          // R ring prefetch
    float adjv[3];
#pragma unroll
    for (int rt = 0; rt < 3; ++rt) {
      int T = (s - it0 - rt) & 63;
      adjv[rt] = adj[n * 1024 + T * 16 + lr];
    }
    f32x4 acc0 = {0.f, 0.f, 0.f, 0.f}, acc1 = {0.f, 0.f, 0.f, 0.f};
    if (!PRO) {
      constexpr int KB = U & 1;
#pragma unroll
      for (int kc = 0; kc < 2; ++kc) {
        acc0 = mfma16(Ah[0][kc], Kh[KB][kc], acc0);
        acc1 = mfma16(Ah[1][kc], Kh[KB][kc], acc1);
        acc0 = mfma16(Al[0][kc], Kh[KB][kc], acc0);
        acc1 = mfma16(Al[1][kc], Kh[KB][kc], acc1);
        acc0 = mfma16(Ah[0][kc], Kl[KB][kc], acc0);
        acc1 = mfma16(Ah[1][kc], Kl[KB][kc], acc1);
      }
    }
    // Bsum row-tiles rt=0..2 (rows i0+16rt .. +15), scatter into window.
    auto bs = [&](auto RT) {
      constexpr int rt = decltype(RT)::value;
      constexpr int SL = (U - rt + 4) & 3;
      if (it0 + rt > 63) return;                      // last i-block: no rows 1024+
      f32x4 aB = {0.f, 0.f, 0.f, 0.f};
#pragma unroll
      for (int kc = 0; kc < 2; ++kc) {
        aB = mfma16(Ah[rt][kc], Rh[SL][kc], aB);
        aB = mfma16(Al[rt][kc], Rh[SL][kc], aB);
        aB = mfma16(Ah[rt][kc], Rl[SL][kc], aB);
      }
      const int T = (s - it0 - rt) & 63;
      const int vb = T * 16 + lr + i0 + rt * 16 + 4 * lh;  // jj + i' (reg r adds)
#pragma unroll
      for (int r = 0; r < 4; ++r) {
        int uu = vb + r;
        bool b1 = (uu >= 1023);                       // band1: j=u-1023,row=i'
        int rowL = rt * 16 + 4 * lh + r - (b1 ? 0 : 1);  // band2: j=u+1,row=i'-1
        int colS = (uu + 1) & 63;                     // same slot either band
        float val = aB[r] + adjv[rt];
        bool ok = (rowL >= 0) && (rowL < 32);
        if (PRO) ok = ok && b1;
        if (ok) win[w][rowL][colS] = val;
      }
    };
    bs(IC<0>{}); bs(IC<1>{}); bs(IC<2>{});
    if (PRO) return;
    __syncthreads();                                  // (d) scatter visible
    // e1: stage AC transpose + zero window half (s+3)&3
#pragma unroll
    for (int r = 0; r < 4; ++r) {
      outb[w][4 * lh + r][lr] = acc0[r];
      outb[w][16 + 4 * lh + r][lr] = acc1[r];
    }
    {
      constexpr int Z = (U + 3) & 3;
      int row = (tid & 63) >> 1, cc = (tid & 1) * 8;
      float4 z = {0.f, 0.f, 0.f, 0.f};
      *(float4*)&win[w][row][Z * 16 + cc] = z;
      *(float4*)&win[w][row][Z * 16 + cc + 4] = z;
    }
    __syncthreads();                                  // (f)
    // e2: out[i, 16s+colL, c0..c0+7] = AC + BD, 32B contiguous per thread
    {
      const int row = tid >> 4, colL = tid & 15;
      const int colS = ((U & 3) * 16) | colL;
      float vv[8];
#pragma unroll
      for (int cl = 0; cl < 8; ++cl)
        vv[cl] = outb[cl][row][colL] + win[cl][row][colS];
      size_t base = ((size_t)(i0 + row) * 1024 + (size_t)(s * 16 + colL)) * 64 + c0;
      float4 o0 = {vv[0], vv[1], vv[2], vv[3]};
      float4 o1 = {vv[4], vv[5], vv[6], vv[7]};
      *(float4*)(out + base) = o0;
      *(float4*)(out + base + 4) = o1;
    }
  };

  // prologue: preload ring slots for "step -1", run masked boundary step
  loadR(IC<3>{}, (63 - it0) & 63);
  loadR(IC<2>{}, (62 - it0) & 63);
  loadR(IC<1>{}, (61 - it0) & 63);
  __syncthreads();                                    // window zero visible
  body(IC<3>{}, IC<1>{}, -1);
  __syncthreads();                                    // prologue scatter visible

  for (int s4 = 0; s4 < 64; s4 += 4) {
    body(IC<0>{}, IC<0>{}, s4 + 0);
    body(IC<1>{}, IC<0>{}, s4 + 1);
    body(IC<2>{}, IC<0>{}, s4 + 2);
    body(IC<3>{}, IC<0>{}, s4 + 3);
  }
}

// ---------------- host ----------------
extern "C" void kernel_launch(void* const* d_in, const int* in_sizes, int n_in,
                              void* d_out, int out_size, void* d_ws, size_t ws_size,
                              hipStream_t stream) {
  const float* wq  = (const float*)d_in[0];   // (1024,4,16,64)
  const float* wk  = (const float*)d_in[1];   // (1024,4,16,64)
  const float* re  = (const float*)d_in[2];   // (1024,16,64)
  const float* rwb = (const float*)d_in[3];   // (16,64)
  const float* rb  = (const float*)d_in[4];   // (1024,16)
  float* out = (float*)d_out;                 // (1024,1024,4,16)
  char* ws = (char*)d_ws;
  float* adj          = (float*)ws;                              // 64 KB
  unsigned short* Kp  = (unsigned short*)(ws + 65536);           // 16 MB
  unsigned short* Rp  = (unsigned short*)(ws + 65536 + 16777216);// 4 MB
  hipLaunchKernelGGL(k_adj,  dim3(64),   dim3(256), 0, stream, re, rwb, rb, adj);
  hipLaunchKernelGGL(k_pack, dim3(5120), dim3(256), 0, stream, wk, re, Kp, Rp);
  hipLaunchKernelGGL(k_main, dim3(256),  dim3(512), 0, stream, wq, rwb, Kp, Rp, adj, out);
}